// Round 10
// baseline (596.493 us; speedup 1.0000x reference)
//
#include <hip/hip_runtime.h>

// GlobalMaxAvgPool: segment max + segment mean, N=2e6, C=128, B=32, ids sorted.
// Memory-bound: 1.03 GB read -> floor ~165 us @ 6.3 TB/s.
// R10 = R9 (NT loads on champion structure: block-contiguous chunk, 8-row slot
// interleave, 8-deep strided NT unroll, LDS id-slice boundary detect, zero hot
// atomics) with the reduce FUSED: completion counter + device fences; blocks
// 0..B-1 spin (s_sleep) until all blocks signal, then each reduces one segment
// in parallel. Removes the dependent gp_reduce dispatch + graph gap.

using f32x4 = __attribute__((ext_vector_type(4))) float;
#define INFF __builtin_huge_valf()

#define BLOCKS 2048
#define MAXR   32        // max runs per block == B (ids ascending, <=32 values)
#define SENT   0x7fffffff

// ws layout: hdr int2[BLOCKS*MAXR] at 0 (512 KB); counter at 896 KB; part at 1 MB
#define OFF_CNT  (896u << 10)
#define OFF_PART (1u << 20)

#define ACC(f) do { \
    vmax[0] = fmaxf(vmax[0], (f)[0]); \
    vmax[1] = fmaxf(vmax[1], (f)[1]); \
    vmax[2] = fmaxf(vmax[2], (f)[2]); \
    vmax[3] = fmaxf(vmax[3], (f)[3]); \
    vsum += (f); } while (0)

// C==128: 32 lanes x float4 = one row; 8 row-slots stride-8 interleave.
__global__ __launch_bounds__(256, 8)
void gp_fused(const float* __restrict__ feat, const int* __restrict__ ids,
              int2* __restrict__ hdr, float* __restrict__ part,
              int* __restrict__ counter, float* __restrict__ out,
              int N, int chunk, int nblocks, int B) {
    const int t     = threadIdx.x;
    const int slot  = t >> 5;        // 0..7
    const int lane5 = t & 31;
    const int c0    = lane5 * 4;

    __shared__ int   sids[1024];
    __shared__ int   srb[MAXR + 2];
    __shared__ int   sbuf[MAXR];
    __shared__ int   snb;
    __shared__ float lmax[8][132];   // +4 pad
    __shared__ float lsum[8][132];

    int start = blockIdx.x * chunk;
    int end   = start + chunk;
    if (end > N) end = N;
    int len = end - start;

    if (len > 0) {
        // local id slice -> LDS (coalesced 4KB)
        for (int i = t; i < len; i += 256) sids[i] = ids[start + i];
        if (t == 0) snb = 0;
        __syncthreads();
        for (int i = t; i < len; i += 256)
            if (i > 0 && sids[i] != sids[i - 1]) {
                int p = atomicAdd(&snb, 1);   // p <= 30 < MAXR (B=32)
                sbuf[p] = i;
            }
        __syncthreads();
        int nb = snb;                         // uniform
        if (t == 0) {
            for (int a = 1; a < nb; ++a) {    // insertion sort (tiny)
                int v = sbuf[a]; int j2 = a - 1;
                while (j2 >= 0 && sbuf[j2] > v) { sbuf[j2 + 1] = sbuf[j2]; --j2; }
                sbuf[j2 + 1] = v;
            }
            srb[0] = 0;
            for (int a = 0; a < nb; ++a) srb[a + 1] = sbuf[a];
            srb[nb + 1] = len;
        }
        __syncthreads();

        const f32x4* __restrict__ frow = reinterpret_cast<const f32x4*>(feat);

        for (int j = 0; j <= nb; ++j) {       // uniform run loop
            int lrs = srb[j], lre = srb[j + 1];
            int seg = sids[lrs];
            int rs = start + lrs, re = start + lre;

            f32x4 vmax = {-INFF, -INFF, -INFF, -INFF};
            f32x4 vsum = {0.f, 0.f, 0.f, 0.f};

            int r = rs + slot;
            // 8 outstanding NT loads at 4KB stride (rows r, r+8, .., r+56)
            for (; r + 56 < re; r += 64) {
                int b0 = r * 32 + lane5;           // fits 32-bit (N*32 = 64M)
                f32x4 f0 = __builtin_nontemporal_load(&frow[b0 +    0]);
                f32x4 f1 = __builtin_nontemporal_load(&frow[b0 +  256]);
                f32x4 f2 = __builtin_nontemporal_load(&frow[b0 +  512]);
                f32x4 f3 = __builtin_nontemporal_load(&frow[b0 +  768]);
                f32x4 f4 = __builtin_nontemporal_load(&frow[b0 + 1024]);
                f32x4 f5 = __builtin_nontemporal_load(&frow[b0 + 1280]);
                f32x4 f6 = __builtin_nontemporal_load(&frow[b0 + 1536]);
                f32x4 f7 = __builtin_nontemporal_load(&frow[b0 + 1792]);
                ACC(f0); ACC(f1); ACC(f2); ACC(f3);
                ACC(f4); ACC(f5); ACC(f6); ACC(f7);
            }
            #pragma unroll 4
            for (; r < re; r += 8) {
                f32x4 f = __builtin_nontemporal_load(&frow[r * 32 + lane5]);
                ACC(f);
            }

            lmax[slot][c0 + 0] = vmax[0]; lmax[slot][c0 + 1] = vmax[1];
            lmax[slot][c0 + 2] = vmax[2]; lmax[slot][c0 + 3] = vmax[3];
            lsum[slot][c0 + 0] = vsum[0]; lsum[slot][c0 + 1] = vsum[1];
            lsum[slot][c0 + 2] = vsum[2]; lsum[slot][c0 + 3] = vsum[3];
            __syncthreads();

            if (t < 128) {
                float m  = lmax[0][t];
                float su = lsum[0][t];
                #pragma unroll
                for (int s = 1; s < 8; ++s) {
                    m   = fmaxf(m, lmax[s][t]);
                    su += lsum[s][t];
                }
                size_t base = (size_t)(blockIdx.x * MAXR + j) * 256;
                part[base + t]       = m;
                part[base + 128 + t] = su;
            }
            if (t == 0) hdr[blockIdx.x * MAXR + j] = make_int2(seg, lre - lrs);
            __syncthreads();
        }
        for (int j = nb + 1 + t; j < MAXR; j += 256)
            hdr[blockIdx.x * MAXR + j] = make_int2(SENT, 0);
    } else {
        for (int j = t; j < MAXR; j += 256)
            hdr[blockIdx.x * MAXR + j] = make_int2(SENT, 0);
    }

    // ---- completion protocol ----
    __threadfence();                 // device-scope release of hdr/part stores
    __syncthreads();                 // all threads fenced before signal
    if (t == 0) atomicAdd(counter, 1);          // device-scope (m20)

    if (blockIdx.x >= B) return;

    // blocks 0..B-1: wait for all blocks, then reduce segment b = blockIdx.x
    if (t == 0) {
        while (__hip_atomic_load(counter, __ATOMIC_ACQUIRE,
                                 __HIP_MEMORY_SCOPE_AGENT) < nblocks)
            __builtin_amdgcn_s_sleep(8);
    }
    __syncthreads();
    __threadfence();                 // acquire side: discard stale lines

    int b = blockIdx.x;
    // binary search block range on monotonic F[k] = hdr[k*MAXR].x
    int lo = 0, hi = nblocks;
    while (lo < hi) { int mid = (lo + hi) >> 1; if (hdr[mid * MAXR].x < b) lo = mid + 1; else hi = mid; }
    int a = lo > 0 ? lo - 1 : 0;
    int lo2 = lo, hi2 = nblocks;
    while (lo2 < hi2) { int mid = (lo2 + hi2) >> 1; if (hdr[mid * MAXR].x < b + 1) lo2 = mid + 1; else hi2 = mid; }
    int c = lo2 - 1;

    float m  = -INFF;
    float su = 0.f;
    int   cnt = 0;
    for (int k = a; k <= c; ++k) {
        for (int r2 = 0; r2 < MAXR; ++r2) {
            int2 h = hdr[k * MAXR + r2];          // uniform -> broadcast
            if (h.x == b) {
                float v = part[(size_t)(k * MAXR + r2) * 256 + t];
                m   = fmaxf(m, v);    // meaningful when t<128
                su += v;              // meaningful when t>=128
                cnt += h.y;
            } else if (h.x > b) break;            // runs ascending + sentinel
        }
    }
    out[b * 256 + t] = (t < 128) ? m : su / fmaxf((float)cnt, 1.0f);
}

extern "C" void kernel_launch(void* const* d_in, const int* in_sizes, int n_in,
                              void* d_out, int out_size, void* d_ws, size_t ws_size,
                              hipStream_t stream) {
    const float* feat = (const float*)d_in[0];
    const int*   ids  = (const int*)d_in[1];
    int N = in_sizes[1];
    int C = (N > 0) ? (in_sizes[0] / N) : 128;   // 128
    int B = out_size / (2 * C);                  // 32
    float* out_f = (float*)d_out;

    char*  wsb     = (char*)d_ws;
    int2*  hdr     = (int2*)wsb;                 // BLOCKS*MAXR int2 (512 KB)
    int*   counter = (int*)(wsb + OFF_CNT);
    float* part    = (float*)(wsb + OFF_PART);   // BLOCKS*MAXR*256 floats (64 MB)

    int chunk = (N + BLOCKS - 1) / BLOCKS;       // 977

    hipMemsetAsync(counter, 0, sizeof(int), stream);   // graph-capturable
    gp_fused<<<BLOCKS, 256, 0, stream>>>(feat, ids, hdr, part, counter, out_f,
                                         N, chunk, BLOCKS, B);
}

// Round 11
// 173.003 us; speedup vs baseline: 3.4479x; 3.4479x over previous
//
#include <hip/hip_runtime.h>

// GlobalMaxAvgPool: segment max + segment mean, N=2e6, C=128, B=32, ids sorted.
// Memory-bound: 1.03 GB read -> floor ~165 us @ 6.3 TB/s.
// R11 = R9 champion (block-contiguous chunk, 8-row slot interleave, 8-deep
// strided NT unroll, LDS id-slice boundary detect, zero hot atomics, separate
// tiny reduce kernel -- R10's fused spin cost 3x, reverted) with ONE change:
// BLOCKS 2048 -> 512 (2 blocks/CU, 8 waves/CU). Theory: fills hit 6.5 TB/s at
// ~3.4 waves/CU; 32 waves/CU x 8 outstanding NT loads oversubscribes the
// memory queues 10x (256 KB in flight/CU vs ~22 KB needed) -> arbiter
// contention. Fewer, longer streams should serve channels better.

using f32x4 = __attribute__((ext_vector_type(4))) float;
#define INFF __builtin_huge_valf()

#define BLOCKS 512
#define CHMAX  4096      // max chunk rows (N=2M/512 = 3907)
#define MAXR   32        // max runs per block == B (ids ascending, <=32 values)
#define SENT   0x7fffffff

// ws layout: hdr int2[BLOCKS*MAXR] at 0 (128 KB); partials at 1 MB (16.8 MB)
#define OFF_PART (1u << 20)

#define ACC(f) do { \
    vmax[0] = fmaxf(vmax[0], (f)[0]); \
    vmax[1] = fmaxf(vmax[1], (f)[1]); \
    vmax[2] = fmaxf(vmax[2], (f)[2]); \
    vmax[3] = fmaxf(vmax[3], (f)[3]); \
    vsum += (f); } while (0)

// C==128: 32 lanes x float4 = one row; 8 row-slots stride-8 interleave.
__global__ __launch_bounds__(256, 2)
void gp_main(const float* __restrict__ feat, const int* __restrict__ ids,
             int2* __restrict__ hdr, float* __restrict__ part, int N, int chunk) {
    const int t     = threadIdx.x;
    const int slot  = t >> 5;        // 0..7
    const int lane5 = t & 31;
    const int c0    = lane5 * 4;

    __shared__ int   sids[CHMAX];
    __shared__ int   srb[MAXR + 2];  // run boundaries (local row idx)
    __shared__ int   sbuf[MAXR];
    __shared__ int   snb;
    __shared__ float lmax[8][132];   // +4 pad
    __shared__ float lsum[8][132];

    int start = blockIdx.x * chunk;
    int end   = start + chunk;
    if (end > N) end = N;
    int len = end - start;

    if (len <= 0) {
        for (int j = t; j < MAXR; j += 256)
            hdr[blockIdx.x * MAXR + j] = make_int2(SENT, 0);
        return;
    }

    // local id slice -> LDS (coalesced ~15.6 KB)
    for (int i = t; i < len; i += 256) sids[i] = ids[start + i];
    if (t == 0) snb = 0;
    __syncthreads();

    // boundary detect (parallel; LDS-atomic order canonicalized by sort)
    for (int i = t; i < len; i += 256)
        if (i > 0 && sids[i] != sids[i - 1]) {
            int p = atomicAdd(&snb, 1);   // p <= 30 < MAXR (B=32)
            sbuf[p] = i;
        }
    __syncthreads();
    int nb = snb;                         // uniform
    if (t == 0) {
        for (int a = 1; a < nb; ++a) {    // insertion sort (tiny)
            int v = sbuf[a]; int j2 = a - 1;
            while (j2 >= 0 && sbuf[j2] > v) { sbuf[j2 + 1] = sbuf[j2]; --j2; }
            sbuf[j2 + 1] = v;
        }
        srb[0] = 0;
        for (int a = 0; a < nb; ++a) srb[a + 1] = sbuf[a];
        srb[nb + 1] = len;
    }
    __syncthreads();

    const f32x4* __restrict__ frow = reinterpret_cast<const f32x4*>(feat);

    for (int j = 0; j <= nb; ++j) {       // uniform run loop
        int lrs = srb[j], lre = srb[j + 1];
        int seg = sids[lrs];
        int rs = start + lrs, re = start + lre;

        f32x4 vmax = {-INFF, -INFF, -INFF, -INFF};
        f32x4 vsum = {0.f, 0.f, 0.f, 0.f};

        int r = rs + slot;
        // 8 outstanding NT loads at 4KB stride (rows r, r+8, .., r+56)
        for (; r + 56 < re; r += 64) {
            int b0 = r * 32 + lane5;               // fits 32-bit (N*32 = 64M)
            f32x4 f0 = __builtin_nontemporal_load(&frow[b0 +    0]);
            f32x4 f1 = __builtin_nontemporal_load(&frow[b0 +  256]);
            f32x4 f2 = __builtin_nontemporal_load(&frow[b0 +  512]);
            f32x4 f3 = __builtin_nontemporal_load(&frow[b0 +  768]);
            f32x4 f4 = __builtin_nontemporal_load(&frow[b0 + 1024]);
            f32x4 f5 = __builtin_nontemporal_load(&frow[b0 + 1280]);
            f32x4 f6 = __builtin_nontemporal_load(&frow[b0 + 1536]);
            f32x4 f7 = __builtin_nontemporal_load(&frow[b0 + 1792]);
            ACC(f0); ACC(f1); ACC(f2); ACC(f3);
            ACC(f4); ACC(f5); ACC(f6); ACC(f7);
        }
        // remainder: same stride, NT as well
        #pragma unroll 4
        for (; r < re; r += 8) {
            f32x4 f = __builtin_nontemporal_load(&frow[r * 32 + lane5]);
            ACC(f);
        }

        // block LDS reduce: 8 contributors per channel
        lmax[slot][c0 + 0] = vmax[0]; lmax[slot][c0 + 1] = vmax[1];
        lmax[slot][c0 + 2] = vmax[2]; lmax[slot][c0 + 3] = vmax[3];
        lsum[slot][c0 + 0] = vsum[0]; lsum[slot][c0 + 1] = vsum[1];
        lsum[slot][c0 + 2] = vsum[2]; lsum[slot][c0 + 3] = vsum[3];
        __syncthreads();

        if (t < 128) {
            float m  = lmax[0][t];
            float su = lsum[0][t];
            #pragma unroll
            for (int s = 1; s < 8; ++s) {
                m   = fmaxf(m, lmax[s][t]);
                su += lsum[s][t];
            }
            size_t base = (size_t)(blockIdx.x * MAXR + j) * 256;
            part[base + t]       = m;
            part[base + 128 + t] = su;
        }
        if (t == 0) hdr[blockIdx.x * MAXR + j] = make_int2(seg, lre - lrs);
        __syncthreads();
    }
    // sentinel unused slots every call (ws not re-poisoned; determinism)
    for (int j = nb + 1 + t; j < MAXR; j += 256)
        hdr[blockIdx.x * MAXR + j] = make_int2(SENT, 0);
}

// One block per segment. F[k] = hdr[k*MAXR].x monotonic in k -> binary search
// block range, scan with early break. hdr/partials L2-hot. Deterministic.
__global__ void gp_reduce(const int2* __restrict__ hdr,
                          const float* __restrict__ part,
                          float* __restrict__ out, int nblocks) {
    int b = blockIdx.x;
    int t = threadIdx.x;   // t<128: max chan t ; t>=128: sum chan t-128

    int lo = 0, hi = nblocks;
    while (lo < hi) { int mid = (lo + hi) >> 1; if (hdr[mid * MAXR].x < b) lo = mid + 1; else hi = mid; }
    int a = lo > 0 ? lo - 1 : 0;
    int lo2 = lo, hi2 = nblocks;
    while (lo2 < hi2) { int mid = (lo2 + hi2) >> 1; if (hdr[mid * MAXR].x < b + 1) lo2 = mid + 1; else hi2 = mid; }
    int c = lo2 - 1;

    float m  = -INFF;
    float su = 0.f;
    int   cnt = 0;
    for (int k = a; k <= c; ++k) {
        for (int r2 = 0; r2 < MAXR; ++r2) {
            int2 h = hdr[k * MAXR + r2];          // uniform -> broadcast
            if (h.x == b) {
                float v = part[(size_t)(k * MAXR + r2) * 256 + t];
                m   = fmaxf(m, v);    // meaningful when t<128
                su += v;              // meaningful when t>=128
                cnt += h.y;
            } else if (h.x > b) break;            // runs ascending + sentinel
        }
    }
    out[b * 256 + t] = (t < 128) ? m : su / fmaxf((float)cnt, 1.0f);
}

extern "C" void kernel_launch(void* const* d_in, const int* in_sizes, int n_in,
                              void* d_out, int out_size, void* d_ws, size_t ws_size,
                              hipStream_t stream) {
    const float* feat = (const float*)d_in[0];
    const int*   ids  = (const int*)d_in[1];
    int N = in_sizes[1];
    int C = (N > 0) ? (in_sizes[0] / N) : 128;   // 128
    int B = out_size / (2 * C);                  // 32
    float* out_f = (float*)d_out;

    char*  wsb  = (char*)d_ws;
    int2*  hdr  = (int2*)wsb;                    // BLOCKS*MAXR int2 (128 KB)
    float* part = (float*)(wsb + OFF_PART);      // BLOCKS*MAXR*256 floats (16.8 MB)

    int chunk = (N + BLOCKS - 1) / BLOCKS;       // 3907

    gp_main<<<BLOCKS, 256, 0, stream>>>(feat, ids, hdr, part, N, chunk);
    gp_reduce<<<B, 256, 0, stream>>>(hdr, part, out_f, BLOCKS);
}